// Round 4
// baseline (140.767 us; speedup 1.0000x reference)
//
#include <hip/hip_runtime.h>
#include <hip/hip_cooperative_groups.h>

namespace cg = cooperative_groups;

#define T_HOR 5
#define G0    40                 // first sync after 40 iterations (n* estimated 41-45)
#define NT    15                 // then 15 groups of 4 -> cap 40 + 60 = 100 = LQR_ITER
#define EPSC  0.01f

// One LQR sweep for ONE 2-state subsystem (p' = p + 0.1 v, v' = 0.75 v + 0.5(ua-ub)).
// Scalar f32 body — identical codegen to the proven R2 kernel, halved per thread.
__device__ __forceinline__ float iter_once(
    const float (&c0)[T_HOR], const float (&c1)[T_HOR],
    const float (&gp)[T_HOR], const float (&hp)[T_HOR],
    float xi_p, float xi_v, float pc_p, float pc_v,
    float (&ua)[T_HOR], float (&ub)[T_HOR])
{
    // rollout
    float xp[T_HOR], xv[T_HOR];
    xp[0] = xi_p; xv[0] = xi_v;
    #pragma unroll
    for (int t = 0; t < T_HOR-1; ++t) {
        xp[t+1] = xp[t] + 0.1f*xv[t];
        xv[t+1] = 0.75f*xv[t] + 0.5f*(ua[t]-ub[t]);
    }

    // backward affine pass (quadratic Riccati part is compile-time constant)
    float ka[T_HOR], kb[T_HOR];
    float vp = 0.f, vv = 0.f;
    #pragma unroll
    for (int t = T_HOR-1; t >= 0; --t) {
        float qa = 0.01f + 0.1f*ua[t] + 0.5f*vv;
        float qb = 0.01f + 0.1f*ub[t] - 0.5f*vv;
        ka[t] = -(c0[t]*qa + c1[t]*qb);
        kb[t] = -(c1[t]*qa + c0[t]*qb);
        float qxp = (pc_p + xp[t]) + vp;
        float qxv = (pc_v + 0.1f*xv[t]) + 0.1f*vp + 0.75f*vv;
        float dq = qa - qb;
        vp = qxp - gp[t]*dq;
        vv = qxv - hp[t]*dq;
    }

    // forward pass with clip
    float delta = 0.f, dp = 0.f, dv = 0.f;
    #pragma unroll
    for (int t = 0; t < T_HOR; ++t) {
        float phi = gp[t]*dp + hp[t]*dv;
        float na = fminf(fmaxf(ua[t] + (ka[t] - phi), 0.f), 1.f);
        float nb = fminf(fmaxf(ub[t] + (kb[t] + phi), 0.f), 1.f);
        float dua = na - ua[t], dub = nb - ub[t];
        delta = fmaxf(delta, fmaxf(fabsf(dua), fabsf(dub)));
        float ndp = dp + 0.1f*dv;
        float ndv = 0.75f*dv + 0.5f*(dua - dub);
        dp = ndp; dv = ndv;
        ua[t] = na; ub[t] = nb;
    }
    return delta;
}

__global__ __launch_bounds__(256)
void mpc_iter_kernel(const float* __restrict__ x_init,
                     const float* __restrict__ xd,
                     float2* __restrict__ out,
                     unsigned long long* __restrict__ gmask0,
                     int* __restrict__ gmaskT)
{
    cg::grid_group grid = cg::this_grid();
    const int tid = blockIdx.x * 256 + threadIdx.x;
    const int b = tid >> 1;      // batch element
    const int s = tid & 1;       // subsystem 0: (p1,v1,u0,u1)  1: (p2,v2,u2,u3)

    // in-kernel workspace zeroing (replaces memset graph node)
    if (threadIdx.x == 0 && blockIdx.x == 0) {
        *gmask0 = 0ull;
        #pragma unroll
        for (int g = 0; g < NT; ++g) gmaskT[g] = 0;
    }

    const float SQ01 = 0.31622776601683794f;  // sqrt(0.1)
    const float xi_p = x_init[4*b + s];
    const float xi_v = x_init[4*b + 2 + s];
    const float pc_p = -xd[4*b + s];
    const float pc_v = -SQ01 * xd[4*b + 2 + s];

    // Batch-independent Riccati gain schedule (constant-folds at compile time)
    float c0[T_HOR], c1[T_HOR], gp[T_HOR], hp[T_HOR];
    {
        float Vpp = 0.f, Vpv = 0.f, Vvv = 0.f;
        #pragma unroll
        for (int t = T_HOR-1; t >= 0; --t) {
            float ss = 0.25f * Vvv;
            float tw = 0.1f + 2.f*ss;
            float dd = 0.1f * tw;
            c0[t] = (0.1f + ss) / dd;
            c1[t] = ss / dd;
            float g = 0.5f * Vpv;
            float h = 0.05f * Vpv + 0.375f * Vvv;
            float inv = 1.f / tw;
            gp[t] = g * inv;
            hp[t] = h * inv;
            float nVpp = 1.0f + Vpp - 2.f*g*gp[t];
            float nVpv = 0.1f*Vpp + 0.75f*Vpv - 2.f*g*hp[t];
            float nVvv = 0.1f + 0.01f*Vpp + 0.15f*Vpv + 0.5625f*Vvv - 2.f*h*hp[t];
            Vpp = nVpp; Vpv = nVpv; Vvv = nVvv;
        }
    }

    float ua[T_HOR] = {0,0,0,0,0}, ub[T_HOR] = {0,0,0,0,0};

    grid.sync();   // workspace zeroing visible before any atomicOr

    float2 result;
    bool done = false;

    // ---- group 0: G0 iterations, 64-bit convergence mask, one sync
    unsigned long long mask = 0ull;
    for (int j = 0; j < G0; ++j) {
        float d = iter_once(c0, c1, gp, hp, xi_p, xi_v, pc_p, pc_v, ua, ub);
        mask |= (unsigned long long)(d > EPSC ? 1u : 0u) << j;
    }
    int mlo = __syncthreads_or((int)(unsigned)mask);
    int mhi = __syncthreads_or((int)(unsigned)(mask >> 32));
    if (threadIdx.x == 0) {
        unsigned long long bm = ((unsigned long long)(unsigned)mhi << 32) | (unsigned)mlo;
        if (bm) __hip_atomic_fetch_or(gmask0, bm, __ATOMIC_RELEASE, __HIP_MEMORY_SCOPE_AGENT);
    }
    grid.sync();
    unsigned long long gm = __hip_atomic_load(gmask0, __ATOMIC_ACQUIRE, __HIP_MEMORY_SCOPE_AGENT);
    int j0 = (int)__builtin_ctzll(~gm);   // first iter with global max<=EPS; <=G0 since bits>=G0 are 0
    if (j0 < G0) {
        // cold path (n* <= G0): replay j0+1 iterations from zeros
        #pragma unroll
        for (int t = 0; t < T_HOR; ++t) { ua[t] = 0.f; ub[t] = 0.f; }
        for (int j = 0; j <= j0; ++j)
            iter_once(c0, c1, gp, hp, xi_p, xi_v, pc_p, pc_v, ua, ub);
        result = make_float2(ua[0], ub[0]);
        done = true;
    }

    // ---- tail: groups of 4, record u[0] per iteration, select by first clear bit
    if (!done) {
        for (int g = 0; g < NT; ++g) {
            float r0[4], r1[4];
            unsigned msk = 0;
            #pragma unroll
            for (int j = 0; j < 4; ++j) {
                float d = iter_once(c0, c1, gp, hp, xi_p, xi_v, pc_p, pc_v, ua, ub);
                r0[j] = ua[0]; r1[j] = ub[0];
                msk |= (d > EPSC ? 1u : 0u) << j;
            }
            int m = __syncthreads_or((int)msk);
            if (threadIdx.x == 0 && m) {
                __hip_atomic_fetch_or(&gmaskT[g], m, __ATOMIC_RELEASE, __HIP_MEMORY_SCOPE_AGENT);
            }
            grid.sync();
            int gmt = __hip_atomic_load(&gmaskT[g], __ATOMIC_ACQUIRE, __HIP_MEMORY_SCOPE_AGENT);
            int jj = (int)__builtin_ctz(~(unsigned)gmt);   // 0..4; bits>=4 are 0
            if (jj < 4) {
                float s0 = r0[0], s1 = r1[0];
                #pragma unroll
                for (int j = 1; j < 4; ++j) {
                    if (j == jj) { s0 = r0[j]; s1 = r1[j]; }
                }
                result = make_float2(s0, s1);
                done = true;
                break;
            }
        }
        if (!done) result = make_float2(ua[0], ub[0]);   // hit 100-iteration cap
    }

    // out element b = [s0.ua, s0.ub, s1.ua, s1.ub] -> float2 slot 2b+s == tid
    out[tid] = result;
}

extern "C" void kernel_launch(void* const* d_in, const int* in_sizes, int n_in,
                              void* d_out, int out_size, void* d_ws, size_t ws_size,
                              hipStream_t stream) {
    const float* x_init = (const float*)d_in[0];
    const float* xd     = (const float*)d_in[1];
    float2* out         = (float2*)d_out;
    unsigned long long* gmask0 = (unsigned long long*)d_ws;
    int* gmaskT         = (int*)((char*)d_ws + 8);

    const int B = in_sizes[0] / 4;          // 65536
    const int threads = 2 * B;              // one thread per subsystem
    void* args[] = { (void*)&x_init, (void*)&xd, (void*)&out, (void*)&gmask0, (void*)&gmaskT };
    dim3 grid(threads / 256), block(256);
    hipLaunchCooperativeKernel((const void*)mpc_iter_kernel, grid, block, args, 0, stream);
}